// Round 13
// baseline (383.936 us; speedup 1.0000x reference)
//
#include <hip/hip_runtime.h>
#include <cstdint>
#include <cstddef>

// B=4 S=2048 E=512 H=8 HD=64.
// Score algebra: S = (xWq+bq)(xWk+bk)^T == x Mt^T x^T + d[j] + row-consts,
// Mt_h = Wk_h Wq_h^T. Q' = x @ Mt^T (half of old x@Wqk); K == x8 itself
// (no K GEMM; K tiles shared across heads -> L2-resident, FETCH 67MB).
// d[j] handled exactly, PIPELINED one iter ahead like vreg (R12 leaked its
// L2 latency into the exp phase). QK^T fp8; PV + V/out GEMMs bf16.
typedef unsigned short u16;
typedef unsigned char u8;
typedef long i64;                                        // 64-bit on amdgcn
typedef __attribute__((ext_vector_type(8))) short bh8;   // 8 bf16 (4 VGPR)
typedef __attribute__((ext_vector_type(4))) float fx4;   // 4 f32 acc

__device__ __forceinline__ u16 f2bf(float f) {           // RNE f32->bf16
  unsigned int u = __float_as_uint(f);
  u += 0x7fffu + ((u >> 16) & 1u);
  return (u16)(u >> 16);
}

// f32 -> OCP e4m3fn with DENORMAL support (band 2^-9..2^-6; flush only <2^-9).
__device__ __forceinline__ u8 f2e4m3(float f) {
  float af = __builtin_fabsf(f);
  unsigned int s = (__float_as_uint(f) >> 24) & 0x80u;
  if (af < 0.015625f) {                       // denormal: round(af/2^-9), 0..8
    unsigned int n = (unsigned int)(af * 512.0f + 0.5f);
    return (u8)(s | n);                       // n==8 carries into exp -> 2^-6
  }
  unsigned int mag = __float_as_uint(af);
  mag += 0x7ffffu + ((mag >> 20) & 1u);       // RNE at 3 mantissa bits
  if (mag >= 0x43E80000u) return (u8)(s | 0x7Eu);  // clamp to 448
  unsigned int e8 = (mag >> 23) - 120u;       // bias 127 -> 7
  unsigned int m8 = (mag >> 20) & 7u;
  return (u8)(s | (e8 << 3) | m8);
}

typedef __attribute__((address_space(1))) void g1_void;
typedef __attribute__((address_space(3))) void l3_void;
__device__ __forceinline__ void gload_lds16(const void* g, const void* lds) {
  __builtin_amdgcn_global_load_lds((g1_void*)(uintptr_t)g,
                                   (l3_void*)(unsigned int)(uintptr_t)lds,
                                   16, 0, 0);
}

__device__ __forceinline__ fx4 MFMA(bh8 a, bh8 b, fx4 c) {
  return __builtin_amdgcn_mfma_f32_16x16x32_bf16(a, b, c, 0, 0, 0);
}
__device__ __forceinline__ fx4 MFMA8(i64 a, i64 b, fx4 c) {
  return __builtin_amdgcn_mfma_f32_16x16x32_fp8_fp8(a, b, c, 0, 0, 0);
}

// ---------------- pre/post processing ----------------
__global__ void cast_x2(const float* __restrict__ in, u16* __restrict__ outb,
                        u8* __restrict__ out8) {
  int i = blockIdx.x * 256 + threadIdx.x;
  float4 f = ((const float4*)in)[i];
  ushort4 u;
  u.x = f2bf(f.x); u.y = f2bf(f.y); u.z = f2bf(f.z); u.w = f2bf(f.w);
  ((ushort4*)outb)[i] = u;
  unsigned int p = (unsigned int)f2e4m3(f.x) | ((unsigned int)f2e4m3(f.y) << 8)
                 | ((unsigned int)f2e4m3(f.z) << 16) | ((unsigned int)f2e4m3(f.w) << 24);
  ((unsigned int*)out8)[i] = p;
}

// Wqk[512][8192] f32 -> wq[(h*512+a)][c]=Wq_h[a,c], wk[(h*512+a)][c]=Wk_h[a,c] (bf16)
__global__ void cast_wqk(const float* __restrict__ Wqk, u16* __restrict__ wq,
                         u16* __restrict__ wk) {
  int idx = blockIdx.x * 256 + threadIdx.x;
  int c4 = (idx & 127) * 4;
  int row = idx >> 7;
  int a = row & 511, h = row >> 9;
  const float* src = Wqk + (size_t)a * 8192 + h * 1024 + c4;
  float4 q = *(const float4*)src;
  float4 k = *(const float4*)(src + 512);
  ushort4 uq = { f2bf(q.x), f2bf(q.y), f2bf(q.z), f2bf(q.w) };
  ushort4 uk = { f2bf(k.x), f2bf(k.y), f2bf(k.z), f2bf(k.w) };
  ((ushort4*)wq)[idx] = uq;
  ((ushort4*)wk)[idx] = uk;
}

// W[R][C] f32 -> Wt[C][R] bf16 (for Wv / Wo)
__global__ void tcast(const float* __restrict__ W, u16* __restrict__ Wt, int R, int C) {
  __shared__ float t[32][33];
  int tx = threadIdx.x, ty = threadIdx.y;
  int c0 = blockIdx.x * 32, r0 = blockIdx.y * 32;
#pragma unroll
  for (int i = 0; i < 4; i++)
    t[ty + i * 8][tx] = W[(size_t)(r0 + ty + i * 8) * C + c0 + tx];
  __syncthreads();
#pragma unroll
  for (int i = 0; i < 4; i++)
    Wt[(size_t)(c0 + ty + i * 8) * R + r0 + tx] = f2bf(t[tx][ty + i * 8]);
}

// ebuf[h*512+a] = Wk_h[a,:].bq_h ; fbuf[h] = bq_h.bk_h
__global__ void ef_kernel(const float* __restrict__ Wqk, const float* __restrict__ bqk,
                          float* __restrict__ ebuf, float* __restrict__ fbuf) {
  int wid = blockIdx.x * 4 + (threadIdx.x >> 6);
  int l = threadIdx.x & 63;
  int h = wid >> 9, a = wid & 511;
  const float* wrow = Wqk + (size_t)a * 8192 + h * 1024 + 512;
  const float* bq = bqk + h * 1024;
  float4 x0 = *(const float4*)(wrow + l * 8), x1 = *(const float4*)(wrow + l * 8 + 4);
  float4 b0 = *(const float4*)(bq + l * 8),  b1 = *(const float4*)(bq + l * 8 + 4);
  float p = x0.x*b0.x + x0.y*b0.y + x0.z*b0.z + x0.w*b0.w
          + x1.x*b1.x + x1.y*b1.y + x1.z*b1.z + x1.w*b1.w;
#pragma unroll
  for (int o = 1; o < 64; o <<= 1) p += __shfl_xor(p, o);
  if (l == 0) ebuf[wid] = p;
  if (wid < 8) {
    const float* bqh = bqk + wid * 1024;
    const float* bkh = bqh + 512;
    float4 q0 = *(const float4*)(bqh + l * 8), q1 = *(const float4*)(bqh + l * 8 + 4);
    float4 k0 = *(const float4*)(bkh + l * 8), k1 = *(const float4*)(bkh + l * 8 + 4);
    float q = q0.x*k0.x + q0.y*k0.y + q0.z*k0.z + q0.w*k0.w
            + q1.x*k1.x + q1.y*k1.y + q1.z*k1.z + q1.w*k1.w;
#pragma unroll
    for (int o = 1; o < 64; o <<= 1) q += __shfl_xor(q, o);
    if (l == 0) fbuf[wid] = q;
  }
}

// dbuf[(b*8+h)*2048+j] = (x[b,j].e_h + f_h)*scale2 - Mb
__global__ void dscale_kernel(const float* __restrict__ x, const float* __restrict__ ebuf,
                              const float* __restrict__ fbuf, float* __restrict__ dbuf) {
  int wid = blockIdx.x * 4 + (threadIdx.x >> 6);
  int l = threadIdx.x & 63;
  const float* xrow = x + (size_t)wid * 512;
  float4 x0 = *(const float4*)(xrow + l * 8), x1 = *(const float4*)(xrow + l * 8 + 4);
  int b = wid >> 11, j = wid & 2047;
#pragma unroll
  for (int h = 0; h < 8; h++) {
    const float* eh = ebuf + h * 512 + l * 8;
    float4 e0 = *(const float4*)eh, e1 = *(const float4*)(eh + 4);
    float p = x0.x*e0.x + x0.y*e0.y + x0.z*e0.z + x0.w*e0.w
            + x1.x*e1.x + x1.y*e1.y + x1.z*e1.z + x1.w*e1.w;
#pragma unroll
    for (int o = 1; o < 64; o <<= 1) p += __shfl_xor(p, o);
    if (l == 0)
      dbuf[((size_t)(b * 8 + h) << 11) + j] = __fmaf_rn(p + fbuf[h], 0.063762531f, -2.0f);
  }
}

// ---------------- GEMM bf16 (m97 128x128/BK64) -----------------------------
// OUT_MODE: 0=f32, 2=fp8 x256 (Mt prep), 3=bf16 scattered per-head V^T.
template <int OUT_MODE>
__global__ __launch_bounds__(256) void gemm_bt(const u16* __restrict__ A,
                                               const u16* __restrict__ Bt,
                                               const float* __restrict__ bias,
                                               void* __restrict__ Cout,
                                               int M, int N, int K,
                                               size_t sA, size_t sB, size_t sC) {
  __shared__ u16 As[128 * 64];
  __shared__ u16 Bs[128 * 64];
  A += blockIdx.z * sA;  Bt += blockIdx.z * sB;
  const int tid = threadIdx.x;
  const int l = tid & 63, w = tid >> 6;
  const int lane15 = l & 15, quad = l >> 4;
  const int wm = (w >> 1) * 64, wn = (w & 1) * 64;
  const int bm = blockIdx.y * 128, bn = blockIdx.x * 128;
  fx4 acc[4][4] = {};

  const int srow = w * 32 + (l >> 3);
  const int scol = ((l & 7) ^ (l >> 3)) * 8;
  const u16* Ag = A + (size_t)(bm + srow) * K + scol;
  const u16* Bg = Bt + (size_t)(bn + srow) * K + scol;

  for (int kt = 0; kt < K; kt += 64) {
    __syncthreads();
#pragma unroll
    for (int c = 0; c < 4; c++) {
      gload_lds16(Ag + (size_t)(c * 8) * K + kt, As + (w * 32 + c * 8) * 64);
      gload_lds16(Bg + (size_t)(c * 8) * K + kt, Bs + (w * 32 + c * 8) * 64);
    }
    __syncthreads();
#pragma unroll
    for (int kk8 = 0; kk8 < 8; kk8 += 4) {
      bh8 a[4], b[4];
#pragma unroll
      for (int mi = 0; mi < 4; mi++) {
        int r = wm + mi * 16 + lane15;
        a[mi] = *(const bh8*)(As + r * 64 + (((kk8 + quad) ^ (r & 7)) * 8));
      }
#pragma unroll
      for (int ni = 0; ni < 4; ni++) {
        int r = wn + ni * 16 + lane15;
        b[ni] = *(const bh8*)(Bs + r * 64 + (((kk8 + quad) ^ (r & 7)) * 8));
      }
#pragma unroll
      for (int mi = 0; mi < 4; mi++)
#pragma unroll
        for (int ni = 0; ni < 4; ni++)
          acc[mi][ni] = MFMA(a[mi], b[ni], acc[mi][ni]);
    }
  }
#pragma unroll
  for (int mi = 0; mi < 4; mi++)
#pragma unroll
    for (int ni = 0; ni < 4; ni++) {
      int col = bn + wn + ni * 16 + lane15;
      float bv = bias ? bias[col] : 0.0f;
#pragma unroll
      for (int r = 0; r < 4; r++) {
        int row = bm + wm + mi * 16 + quad * 4 + r;
        float v = acc[mi][ni][r] + bv;
        if (OUT_MODE == 3)
          ((u16*)Cout)[((size_t)((row >> 11) * 512 + col) << 11) + (row & 2047)] = f2bf(v);
        else if (OUT_MODE == 2)
          ((u8*)Cout)[blockIdx.z * sC + (size_t)row * N + col] = f2e4m3(v * 256.0f);
        else ((float*)Cout)[(size_t)row * N + col] = v;
      }
    }
}

// ---------------- GEMM fp8 (BK=128): Q' = (x8 * Mt8^T) * 2^-8 -> fp8 -------
__global__ __launch_bounds__(256) void gemm8_bt(const u8* __restrict__ A,
                                                const u8* __restrict__ Bt,
                                                const float* __restrict__ bias,
                                                u8* __restrict__ Cout,
                                                int M, int N, int K) {
  __shared__ u8 As[128 * 128];
  __shared__ u8 Bs[128 * 128];
  const int tid = threadIdx.x;
  const int l = tid & 63, w = tid >> 6;
  const int lane15 = l & 15, quad = l >> 4;
  const int wm = (w >> 1) * 64, wn = (w & 1) * 64;
  const int bm = blockIdx.y * 128, bn = blockIdx.x * 128;
  fx4 acc[4][4] = {};

  const int srow = w * 32 + (l >> 3);
  const int scol = ((l & 7) ^ ((l >> 3) & 7)) * 16;
  const u8* Ag = A + (size_t)(bm + srow) * K + scol;
  const u8* Bg = Bt + (size_t)(bn + srow) * K + scol;

  for (int kt = 0; kt < K; kt += 128) {
    __syncthreads();
#pragma unroll
    for (int c = 0; c < 4; c++) {
      gload_lds16(Ag + (size_t)(c * 8) * K + kt, As + (w * 32 + c * 8) * 128);
      gload_lds16(Bg + (size_t)(c * 8) * K + kt, Bs + (w * 32 + c * 8) * 128);
    }
    __syncthreads();
    const int qh = quad >> 1, qb = (quad & 1) * 8;
#pragma unroll
    for (int e = 0; e < 4; e++) {
      i64 a[4], b[4];
#pragma unroll
      for (int mi = 0; mi < 4; mi++) {
        int r = wm + mi * 16 + lane15;
        a[mi] = *(const i64*)(As + r * 128 + (((2 * e + qh) ^ (r & 7)) * 16) + qb);
      }
#pragma unroll
      for (int ni = 0; ni < 4; ni++) {
        int r = wn + ni * 16 + lane15;
        b[ni] = *(const i64*)(Bs + r * 128 + (((2 * e + qh) ^ (r & 7)) * 16) + qb);
      }
#pragma unroll
      for (int mi = 0; mi < 4; mi++)
#pragma unroll
        for (int ni = 0; ni < 4; ni++)
          acc[mi][ni] = MFMA8(a[mi], b[ni], acc[mi][ni]);
    }
  }
#pragma unroll
  for (int mi = 0; mi < 4; mi++)
#pragma unroll
    for (int ni = 0; ni < 4; ni++) {
      int col = bn + wn + ni * 16 + lane15;
      float bv = bias ? bias[col] : 0.0f;
#pragma unroll
      for (int r = 0; r < 4; r++) {
        int row = bm + wm + mi * 16 + quad * 4 + r;
        Cout[(size_t)row * N + col] = f2e4m3(acc[mi][ni][r] * 0.00390625f + bv);
      }
    }
}

// ---------------- flash attention ----------------
// block = (b,h,128 q-rows), 4 waves x 32 q-rows, 52KB LDS -> 3 blocks/CU cap.
// K tile = x8[b] rows (shared across heads, L2-resident). d[j] term pipelined
// ONE ITER AHEAD like vreg (loaded next to V(t+1), consumed at t+1) — R12's
// same-iter d-loads leaked L2 latency into the exp phase. PV pipelined one
// iter behind QK; Ks/Vs double-buffered; Ps wave-private (in-order DS).
__global__ __launch_bounds__(256, 3) void flash_attn(const u8* __restrict__ qp8,
                                                     const u8* __restrict__ x8,
                                                     const u16* __restrict__ vt,
                                                     const float* __restrict__ dbuf,
                                                     u16* __restrict__ vals) {
  __shared__ __align__(16) u8 Ks[2][32 * 512];   // 32KB fp8, chunk-swizzled
  __shared__ __align__(16) u16 Vs[2][64 * 40];   // 10KB bf16, padded rows
  __shared__ __align__(16) u16 Ps[4][32 * 40];   // 10KB per-wave P
  const int tid = threadIdx.x;
  const int l = tid & 63, w = tid >> 6;
  const int lane15 = l & 15, quad = l >> 4;
  const int q0 = blockIdx.x * 128;
  const int h = blockIdx.y, b = blockIdx.z;
  const float scale2 = 0.063762531f;   // (1/sqrt(512)) * log2(e)

  i64 qf[2][16];
#pragma unroll
  for (int mt = 0; mt < 2; mt++) {
    const u8* qrow = qp8 + (size_t)(b * 2048 + q0 + w * 32 + mt * 16 + lane15) * 4096
                   + h * 512 + quad * 8;
#pragma unroll
    for (int t = 0; t < 16; t++) qf[mt][t] = *(const i64*)(qrow + t * 32);
  }

  fx4 accO[2][4] = {};
  float lpart[2][4] = {};

  const u8* kbase = x8 + (size_t)b * 2048 * 512;             // K == x8[b]
  const float* dbase = dbuf + ((size_t)(b * 8 + h) << 11);
  const u16* vrow = vt + (size_t)((b * 8 + h) * 64 + (tid >> 2)) * 2048 + (tid & 3) * 8;
  const int vs_off = (tid >> 2) * 40 + (tid & 3) * 8;

  // prologue: stage Ks(0); vreg holds V(0); dreg holds d(0)
  uint4 vreg = *(const uint4*)vrow;
  float dreg0 = dbase[lane15];
  float dreg1 = dbase[16 + lane15];
#pragma unroll
  for (int c = 0; c < 4; c++) {
    int R0 = w * 8 + 2 * c;
    int r = R0 + (l >> 5);
    gload_lds16(kbase + (size_t)r * 512 + (((l & 31) ^ (r & 7)) * 16),
                &Ks[0][R0 * 512]);
  }

  for (int t = 0; t < 64; t++) {
    const int cb = t & 1, nb = cb ^ 1;
    const int kt0 = t * 32;
    __syncthreads();                   // Ks(t)/Vs(t-1) landed; buffers free

    // PV(t-1) operands: issue early, consumed mid-iter (latency hidden)
    bh8 pf0, pf1, vf0, vf1, vf2, vf3;
    if (t > 0) {
      const u16* vsb = &Vs[(t - 1) & 1][0];           // V(t-1)
      pf0 = *(const bh8*)(&Ps[w][lane15 * 40 + quad * 8]);
      pf1 = *(const bh8*)(&Ps[w][(16 + lane15) * 40 + quad * 8]);
      vf0 = *(const bh8*)(vsb + (lane15)      * 40 + quad * 8);
      vf1 = *(const bh8*)(vsb + (16 + lane15) * 40 + quad * 8);
      vf2 = *(const bh8*)(vsb + (32 + lane15) * 40 + quad * 8);
      vf3 = *(const bh8*)(vsb + (48 + lane15) * 40 + quad * 8);
    }

    *(uint4*)&Vs[cb][vs_off] = vreg;   // stage V(t) (read by PV at iter t+1)

    float dn0 = dreg0, dn1 = dreg1;
    if (t < 63) {                      // stage Ks(t+1); prefetch V(t+1), d(t+1)
#pragma unroll
      for (int c = 0; c < 4; c++) {
        int R0 = w * 8 + 2 * c;
        int r = R0 + (l >> 5);
        gload_lds16(kbase + (size_t)(kt0 + 32 + r) * 512 + (((l & 31) ^ (r & 7)) * 16),
                    &Ks[nb][R0 * 512]);
      }
      vreg = *(const uint4*)(vrow + kt0 + 32);        // V(t+1)
      dn0 = dbase[kt0 + 32 + lane15];                 // d(t+1), used next iter
      dn1 = dbase[kt0 + 48 + lane15];
    }

    // S = Q'*K^T: 32 q-rows x 32 k-cols per wave, E=512 inner (fp8)
    fx4 accS[2][2] = {};
#pragma unroll
    for (int e = 0; e < 16; e++) {
      int slot = (((2 * e + (quad >> 1)) ^ (lane15 & 7)) * 16) + (quad & 1) * 8;
      i64 b0 = *(const i64*)(&Ks[cb][lane15 * 512 + slot]);
      i64 b1 = *(const i64*)(&Ks[cb][(16 + lane15) * 512 + slot]);
      accS[0][0] = MFMA8(qf[0][e], b0, accS[0][0]);
      accS[1][0] = MFMA8(qf[1][e], b0, accS[1][0]);
      accS[0][1] = MFMA8(qf[0][e], b1, accS[0][1]);
      accS[1][1] = MFMA8(qf[1][e], b1, accS[1][1]);
    }

    // PV(t-1): independent accumulates, interleave with QK above
    if (t > 0) {
      accO[0][0] = MFMA(pf0, vf0, accO[0][0]); accO[1][0] = MFMA(pf1, vf0, accO[1][0]);
      accO[0][1] = MFMA(pf0, vf1, accO[0][1]); accO[1][1] = MFMA(pf1, vf1, accO[1][1]);
      accO[0][2] = MFMA(pf0, vf2, accO[0][2]); accO[1][2] = MFMA(pf1, vf2, accO[1][2]);
      accO[0][3] = MFMA(pf0, vf3, accO[0][3]); accO[1][3] = MFMA(pf1, vf3, accO[1][3]);
    }

    // exp2(fma(S, scale2, d[j])) — d includes the -Mb shift (exact bias fold)
#pragma unroll
    for (int mt = 0; mt < 2; mt++)
#pragma unroll
      for (int r = 0; r < 4; r++) {
        float p0 = __builtin_amdgcn_exp2f(__fmaf_rn(accS[mt][0][r], scale2, dreg0));
        float p1 = __builtin_amdgcn_exp2f(__fmaf_rn(accS[mt][1][r], scale2, dreg1));
        lpart[mt][r] += p0 + p1;
        Ps[w][(mt * 16 + quad * 4 + r) * 40 + lane15]      = f2bf(p0);
        Ps[w][(mt * 16 + quad * 4 + r) * 40 + 16 + lane15] = f2bf(p1);
      }
    dreg0 = dn0; dreg1 = dn1;
  }

  {  // tail: PV(63). V(63) is in buffer 63 & 1 == 1.
    const u16* vsb = &Vs[1][0];
    bh8 pf0 = *(const bh8*)(&Ps[w][lane15 * 40 + quad * 8]);
    bh8 pf1 = *(const bh8*)(&Ps[w][(16 + lane15) * 40 + quad * 8]);
#pragma unroll
    for (int di = 0; di < 4; di++) {
      bh8 vf = *(const bh8*)(vsb + (di * 16 + lane15) * 40 + quad * 8);
      accO[0][di] = MFMA(pf0, vf, accO[0][di]);
      accO[1][di] = MFMA(pf1, vf, accO[1][di]);
    }
  }

  // epilogue: reduce row-sums across the 16 lanes, normalize, store
#pragma unroll
  for (int mt = 0; mt < 2; mt++)
#pragma unroll
    for (int r = 0; r < 4; r++) {
      float s = lpart[mt][r];
      s += __shfl_xor(s, 1);
      s += __shfl_xor(s, 2);
      s += __shfl_xor(s, 4);
      s += __shfl_xor(s, 8);
      float inv = 1.0f / s;
      int row = q0 + w * 32 + mt * 16 + quad * 4 + r;
      u16* orow = vals + (size_t)(b * 2048 + row) * 512 + h * 64 + lane15;
#pragma unroll
      for (int di = 0; di < 4; di++) orow[di * 16] = f2bf(accO[mt][di][r] * inv);
    }
}

// ---------------- launch ----------------
extern "C" void kernel_launch(void* const* d_in, const int* in_sizes, int n_in,
                              void* d_out, int out_size, void* d_ws, size_t ws_size,
                              hipStream_t stream) {
  const float* x   = (const float*)d_in[0];
  const float* Wqk = (const float*)d_in[1];
  const float* bqk = (const float*)d_in[2];
  const float* Wv  = (const float*)d_in[3];
  const float* bv  = (const float*)d_in[4];
  const float* Wo  = (const float*)d_in[5];
  const float* bo  = (const float*)d_in[6];
  float* out = (float*)d_out;

  char* ws = (char*)d_ws;                     // total use: ~75 MB
  u16* x_bf  = (u16*)(ws);                    // 8192x512 bf16 (8 MB)
  u8*  x8    = (u8*)(ws + 8388608);           // 8192x512 fp8  (4 MB)
  u16* wq_bf = (u16*)(ws + 12582912);         // [h*512+a][c] bf16 (4 MB)
  u16* wk_bf = (u16*)(ws + 16777216);         // [h*512+a][c] bf16 (4 MB)
  u8*  mt8   = (u8*)(ws + 20971520);          // [h*512+b][a] fp8 x256 (2 MB)
  u16* wvt   = (u16*)(ws + 23068672);         // 512x512
  u16* wot   = (u16*)(ws + 23592960);         // 512x512
  u16* vtbuf = (u16*)(ws + 24117248);         // 32x64x2048 (per-head V^T, 8 MB)
  u16* valsb = (u16*)(ws + 32505856);         // 8192x512 (8 MB)
  u8*  qp8   = (u8*)(ws + 40894464);          // 8192x4096 fp8 Q' (32 MB)
  float* ebuf = (float*)(ws + 74448896);      // 4096 f32
  float* fbuf = (float*)(ws + 74465280);      // 8 f32
  float* dbuf = (float*)(ws + 74465312);      // 32x2048 f32 (256 KB)

  cast_x2<<<4096, 256, 0, stream>>>(x, x_bf, x8);
  cast_wqk<<<2048, 256, 0, stream>>>(Wqk, wq_bf, wk_bf);
  tcast<<<dim3(16, 16), dim3(32, 8), 0, stream>>>(Wv, wvt, 512, 512);
  tcast<<<dim3(16, 16), dim3(32, 8), 0, stream>>>(Wo, wot, 512, 512);
  ef_kernel<<<1024, 256, 0, stream>>>(Wqk, bqk, ebuf, fbuf);
  dscale_kernel<<<2048, 256, 0, stream>>>(x, ebuf, fbuf, dbuf);

  // Mt_h = Wk_h @ Wq_h^T  (batched over h; fp8 x256 out)
  gemm_bt<2><<<dim3(4, 4, 8), 256, 0, stream>>>(wk_bf, wq_bf, nullptr, mt8,
                                                512, 512, 512, 262144, 262144, 262144);
  // Q' = x8 @ Mt8^T  (half the old x@Wqk GEMM; K side is x8 itself)
  gemm8_bt<<<dim3(32, 64), 256, 0, stream>>>(x8, mt8, nullptr, qp8, 8192, 4096, 512);
  // V = x@Wv scattered directly as per-head V^T
  gemm_bt<3><<<dim3(4, 64), 256, 0, stream>>>(x_bf, wvt, bv, vtbuf,
                                              8192, 512, 512, 0, 0, 0);

  flash_attn<<<dim3(16, 8, 4), 256, 0, stream>>>(qp8, x8, vtbuf, dbuf, valsb);

  gemm_bt<0><<<dim3(4, 64), 256, 0, stream>>>(valsb, wot, bo, out,
                                              8192, 512, 512, 0, 0, 0);
}

// Round 14
// 321.968 us; speedup vs baseline: 1.1925x; 1.1925x over previous
//
#include <hip/hip_runtime.h>
#include <cstdint>
#include <cstddef>

// B=4 S=2048 E=512 H=8 HD=64.
// G1 (x@Wqk) in fp8xfp8 MFMA (W scaled x256, descale 2^-8). QK^T fp8;
// PV + other GEMMs bf16. Flash: 52KB LDS -> 3 blocks/CU (Vs 2-buffer,
// V(t) written at iter-t top), PV pipelined one iter behind QK.
// [R14 = verbatim revert to R11, the best measured config: 322.7 us.
//  R12/R13 (score-algebra Q'=x.Mt^T, K=x8) halved G1 FLOPs and collapsed
//  FETCH 180->67MB but leaked d[j]-load latency into flash's critical path
//  both times (350/384 us) — flash is hypersensitive to extra per-iter VMEM.]
typedef unsigned short u16;
typedef unsigned char u8;
typedef long i64;                                        // 64-bit on amdgcn
typedef __attribute__((ext_vector_type(8))) short bh8;   // 8 bf16 (4 VGPR)
typedef __attribute__((ext_vector_type(4))) float fx4;   // 4 f32 acc

__device__ __forceinline__ u16 f2bf(float f) {           // RNE f32->bf16
  unsigned int u = __float_as_uint(f);
  u += 0x7fffu + ((u >> 16) & 1u);
  return (u16)(u >> 16);
}

// RNE f32 -> OCP e4m3fn, flush below 2^-6 to 0. Callers keep |f| in range.
__device__ __forceinline__ u8 f2e4m3(float f) {
  unsigned int u = __float_as_uint(f);
  unsigned int s = (u >> 24) & 0x80u;
  unsigned int mag = u & 0x7fffffffu;
  mag += 0x7ffffu + ((mag >> 20) & 1u);     // RNE at 3 mantissa bits
  if (mag < 0x3C800000u) return (u8)s;      // < 2^-6 -> signed zero
  unsigned int e8 = (mag >> 23) - 120u;     // bias 127 -> 7
  unsigned int m8 = (mag >> 20) & 7u;
  return (u8)(s | (e8 << 3) | m8);
}

typedef __attribute__((address_space(1))) void g1_void;
typedef __attribute__((address_space(3))) void l3_void;
__device__ __forceinline__ void gload_lds16(const void* g, const void* lds) {
  // async global->LDS, 16B/lane; LDS dest = wave-uniform base + lane*16
  __builtin_amdgcn_global_load_lds((g1_void*)(uintptr_t)g,
                                   (l3_void*)(unsigned int)(uintptr_t)lds,
                                   16, 0, 0);
}

__device__ __forceinline__ fx4 MFMA(bh8 a, bh8 b, fx4 c) {
  return __builtin_amdgcn_mfma_f32_16x16x32_bf16(a, b, c, 0, 0, 0);
}
__device__ __forceinline__ fx4 MFMA8(i64 a, i64 b, fx4 c) {
  return __builtin_amdgcn_mfma_f32_16x16x32_fp8_fp8(a, b, c, 0, 0, 0);
}

// ---------------- pre/post processing ----------------
// x f32 -> bf16 (for V-GEMM) and fp8 (for G1)
__global__ void cast_x2(const float* __restrict__ in, u16* __restrict__ outb,
                        u8* __restrict__ out8) {
  int i = blockIdx.x * 256 + threadIdx.x;           // grid sized exactly n/4
  float4 f = ((const float4*)in)[i];
  ushort4 u;
  u.x = f2bf(f.x); u.y = f2bf(f.y); u.z = f2bf(f.z); u.w = f2bf(f.w);
  ((ushort4*)outb)[i] = u;
  unsigned int p = (unsigned int)f2e4m3(f.x) | ((unsigned int)f2e4m3(f.y) << 8)
                 | ((unsigned int)f2e4m3(f.z) << 16) | ((unsigned int)f2e4m3(f.w) << 24);
  ((unsigned int*)out8)[i] = p;
}

// W[R][C] f32 -> Wt[C][R] bf16 (gemm_bt wants B as [N][K])
__global__ void tcast(const float* __restrict__ W, u16* __restrict__ Wt, int R, int C) {
  __shared__ float t[32][33];
  int tx = threadIdx.x, ty = threadIdx.y;
  int c0 = blockIdx.x * 32, r0 = blockIdx.y * 32;
#pragma unroll
  for (int i = 0; i < 4; i++)
    t[ty + i * 8][tx] = W[(size_t)(r0 + ty + i * 8) * C + c0 + tx];
  __syncthreads();
#pragma unroll
  for (int i = 0; i < 4; i++)
    Wt[(size_t)(c0 + ty + i * 8) * R + r0 + tx] = f2bf(t[tx][ty + i * 8]);
}

// W[R][C] f32 -> Wt[C][R] fp8, scaled x256 (exact pow2; descaled in GEMM)
__global__ void tcast8(const float* __restrict__ W, u8* __restrict__ Wt, int R, int C) {
  __shared__ float t[32][33];
  int tx = threadIdx.x, ty = threadIdx.y;
  int c0 = blockIdx.x * 32, r0 = blockIdx.y * 32;
#pragma unroll
  for (int i = 0; i < 4; i++)
    t[ty + i * 8][tx] = W[(size_t)(r0 + ty + i * 8) * C + c0 + tx];
  __syncthreads();
#pragma unroll
  for (int i = 0; i < 4; i++)
    Wt[(size_t)(c0 + ty + i * 8) * R + r0 + tx] = f2e4m3(t[tx][ty + i * 8] * 256.0f);
}

// ---------------- GEMM bf16: C[M][N] = A[M][K] * Bt[N][K]^T + bias --------
// m97 structure: 128x128 tile, BK=64, 4 waves each 64x64 (4x4 of 16x16).
// OUT_MODE: 0 = f32, 1 = bf16, 3 = bf16 scattered as per-head V^T:
// vt[(b*512 + col)*2048 + s].  (R10's operand-swap epilogue regressed; the
// scalar-store epilogue is the measured-best form.)
template <int OUT_MODE>
__global__ __launch_bounds__(256) void gemm_bt(const u16* __restrict__ A,
                                               const u16* __restrict__ Bt,
                                               const float* __restrict__ bias,
                                               void* __restrict__ Cout,
                                               int M, int N, int K) {
  __shared__ u16 As[128 * 64];
  __shared__ u16 Bs[128 * 64];
  const int tid = threadIdx.x;
  const int l = tid & 63, w = tid >> 6;
  const int lane15 = l & 15, quad = l >> 4;
  const int wm = (w >> 1) * 64, wn = (w & 1) * 64;
  const int bm = blockIdx.y * 128, bn = blockIdx.x * 128;
  fx4 acc[4][4] = {};

  const int srow = w * 32 + (l >> 3);
  const int scol = ((l & 7) ^ (l >> 3)) * 8;      // swizzle: slot (l&7) <- chunk (l&7)^(row&7)
  const u16* Ag = A + (size_t)(bm + srow) * K + scol;
  const u16* Bg = Bt + (size_t)(bn + srow) * K + scol;

  for (int kt = 0; kt < K; kt += 64) {
    __syncthreads();
#pragma unroll
    for (int c = 0; c < 4; c++) {
      gload_lds16(Ag + (size_t)(c * 8) * K + kt, As + (w * 32 + c * 8) * 64);
      gload_lds16(Bg + (size_t)(c * 8) * K + kt, Bs + (w * 32 + c * 8) * 64);
    }
    __syncthreads();
#pragma unroll
    for (int kk8 = 0; kk8 < 8; kk8 += 4) {        // kk8 = kk/8, kk in {0,32}
      bh8 a[4], b[4];
#pragma unroll
      for (int mi = 0; mi < 4; mi++) {
        int r = wm + mi * 16 + lane15;
        a[mi] = *(const bh8*)(As + r * 64 + (((kk8 + quad) ^ (r & 7)) * 8));
      }
#pragma unroll
      for (int ni = 0; ni < 4; ni++) {
        int r = wn + ni * 16 + lane15;
        b[ni] = *(const bh8*)(Bs + r * 64 + (((kk8 + quad) ^ (r & 7)) * 8));
      }
#pragma unroll
      for (int mi = 0; mi < 4; mi++)
#pragma unroll
        for (int ni = 0; ni < 4; ni++)
          acc[mi][ni] = MFMA(a[mi], b[ni], acc[mi][ni]);
    }
  }
  // epilogue: C/D layout col=lane&15, row=quad*4+reg  [measured m89/m91]
#pragma unroll
  for (int mi = 0; mi < 4; mi++)
#pragma unroll
    for (int ni = 0; ni < 4; ni++) {
      int col = bn + wn + ni * 16 + lane15;
      float bv = bias[col];
#pragma unroll
      for (int r = 0; r < 4; r++) {
        int row = bm + wm + mi * 16 + quad * 4 + r;
        float v = acc[mi][ni][r] + bv;
        if (OUT_MODE == 3)
          ((u16*)Cout)[((size_t)((row >> 11) * 512 + col) << 11) + (row & 2047)] = f2bf(v);
        else if (OUT_MODE == 1) ((u16*)Cout)[(size_t)row * N + col] = f2bf(v);
        else                    ((float*)Cout)[(size_t)row * N + col] = v;
      }
    }
}

// ---------------- GEMM fp8: C = (A8 * B8t^T) * 2^-8 + bias -> fp8 ----------
// m97 skeleton, BK=128 fp8 (128B rows, 32KB LDS, half the staging calls per
// FLOP of bf16). Swizzle identical to the flash Ks pattern.
__global__ __launch_bounds__(256) void gemm8_bt(const u8* __restrict__ A,
                                                const u8* __restrict__ Bt,
                                                const float* __restrict__ bias,
                                                u8* __restrict__ Cout,
                                                int M, int N, int K) {
  __shared__ u8 As[128 * 128];
  __shared__ u8 Bs[128 * 128];
  const int tid = threadIdx.x;
  const int l = tid & 63, w = tid >> 6;
  const int lane15 = l & 15, quad = l >> 4;
  const int wm = (w >> 1) * 64, wn = (w & 1) * 64;
  const int bm = blockIdx.y * 128, bn = blockIdx.x * 128;
  fx4 acc[4][4] = {};

  // staging: wave w covers rows w*32..+31 in 4 calls of 8 rows x 8 chunks
  const int srow = w * 32 + (l >> 3);
  const int scol = ((l & 7) ^ ((l >> 3) & 7)) * 16;
  const u8* Ag = A + (size_t)(bm + srow) * K + scol;
  const u8* Bg = Bt + (size_t)(bn + srow) * K + scol;

  for (int kt = 0; kt < K; kt += 128) {
    __syncthreads();
#pragma unroll
    for (int c = 0; c < 4; c++) {
      gload_lds16(Ag + (size_t)(c * 8) * K + kt, As + (w * 32 + c * 8) * 128);
      gload_lds16(Bg + (size_t)(c * 8) * K + kt, Bs + (w * 32 + c * 8) * 128);
    }
    __syncthreads();
    const int qh = quad >> 1, qb = (quad & 1) * 8;
#pragma unroll
    for (int e = 0; e < 4; e++) {
      i64 a[4], b[4];
#pragma unroll
      for (int mi = 0; mi < 4; mi++) {
        int r = wm + mi * 16 + lane15;
        a[mi] = *(const i64*)(As + r * 128 + (((2 * e + qh) ^ (r & 7)) * 16) + qb);
      }
#pragma unroll
      for (int ni = 0; ni < 4; ni++) {
        int r = wn + ni * 16 + lane15;
        b[ni] = *(const i64*)(Bs + r * 128 + (((2 * e + qh) ^ (r & 7)) * 16) + qb);
      }
#pragma unroll
      for (int mi = 0; mi < 4; mi++)
#pragma unroll
        for (int ni = 0; ni < 4; ni++)
          acc[mi][ni] = MFMA8(a[mi], b[ni], acc[mi][ni]);
    }
  }
  // epilogue: descale 2^-8 (W was quantized x256), add bias, store fp8
#pragma unroll
  for (int mi = 0; mi < 4; mi++)
#pragma unroll
    for (int ni = 0; ni < 4; ni++) {
      int col = bn + wn + ni * 16 + lane15;
      float bv = bias[col];
#pragma unroll
      for (int r = 0; r < 4; r++) {
        int row = bm + wm + mi * 16 + quad * 4 + r;
        Cout[(size_t)row * N + col] = f2e4m3(acc[mi][ni][r] * 0.00390625f + bv);
      }
    }
}

// ---------------- flash attention ----------------
// block = (b,h,128 q-rows), 4 waves x 32 q-rows, 52KB LDS -> 3 blocks/CU
// (3 waves/SIMD de-phase across the barrier, so MFMA/VALU/LDS phases of
// different blocks overlap — R8's accounting showed the pipes were additive
// at 2 phase-locked waves/SIMD). Vs is 2-buffered: V(t) is ds_written at the
// TOP of iter t from a vreg loaded at t-1; PV(t-1) reads buf (t-1)&1 —
// disjoint, and the next write to that buffer happens after barrier(t+1),
// by which time all readers have passed. PV pipelined one iter behind QK.
// Fixed-max softmax (scores tiny; shift-invariant, exact).
__global__ __launch_bounds__(256, 3) void flash_attn(const u8* __restrict__ qk8,
                                                     const u16* __restrict__ vt,
                                                     u16* __restrict__ vals) {
  __shared__ __align__(16) u8 Ks[2][32 * 512];   // 32KB fp8, chunk-swizzled
  __shared__ __align__(16) u16 Vs[2][64 * 40];   // 10KB bf16, padded rows
  __shared__ __align__(16) u16 Ps[4][32 * 40];   // 10KB per-wave P
  const int tid = threadIdx.x;
  const int l = tid & 63, w = tid >> 6;
  const int lane15 = l & 15, quad = l >> 4;
  const int q0 = blockIdx.x * 128;
  const int h = blockIdx.y, b = blockIdx.z;
  const float scale2 = 0.063762531f;   // (1/sqrt(512)) * log2(e)
  const float Mb = 2.0f;               // fixed shift (log2 domain)

  i64 qf[2][16];
#pragma unroll
  for (int mt = 0; mt < 2; mt++) {
    const u8* qrow = qk8 + (size_t)(b * 2048 + q0 + w * 32 + mt * 16 + lane15) * 8192
                   + h * 1024 + quad * 8;
#pragma unroll
    for (int t = 0; t < 16; t++) qf[mt][t] = *(const i64*)(qrow + t * 32);
  }

  fx4 accO[2][4] = {};
  float lpart[2][4] = {};

  const u8* kbase = qk8 + (size_t)(b * 2048) * 8192 + h * 1024 + 512;
  const u16* vrow = vt + (size_t)((b * 8 + h) * 64 + (tid >> 2)) * 2048 + (tid & 3) * 8;
  const int vs_off = (tid >> 2) * 40 + (tid & 3) * 8;

  // prologue: stage Ks(0); vreg holds V(0)
  uint4 vreg = *(const uint4*)vrow;
#pragma unroll
  for (int c = 0; c < 4; c++) {
    int R0 = w * 8 + 2 * c;
    int r = R0 + (l >> 5);
    gload_lds16(kbase + (size_t)r * 8192 + (((l & 31) ^ (r & 7)) * 16),
                &Ks[0][R0 * 512]);
  }

  for (int t = 0; t < 64; t++) {
    const int cb = t & 1, nb = cb ^ 1;
    const int kt0 = t * 32;
    __syncthreads();                   // Ks(t)/Vs(t-1) landed; buffers free

    // PV(t-1) operands: issue early, consumed mid-iter (latency hidden)
    bh8 pf0, pf1, vf0, vf1, vf2, vf3;
    if (t > 0) {
      const u16* vsb = &Vs[(t - 1) & 1][0];           // V(t-1)
      pf0 = *(const bh8*)(&Ps[w][lane15 * 40 + quad * 8]);
      pf1 = *(const bh8*)(&Ps[w][(16 + lane15) * 40 + quad * 8]);
      vf0 = *(const bh8*)(vsb + (lane15)      * 40 + quad * 8);
      vf1 = *(const bh8*)(vsb + (16 + lane15) * 40 + quad * 8);
      vf2 = *(const bh8*)(vsb + (32 + lane15) * 40 + quad * 8);
      vf3 = *(const bh8*)(vsb + (48 + lane15) * 40 + quad * 8);
    }

    *(uint4*)&Vs[cb][vs_off] = vreg;   // stage V(t) (read by PV at iter t+1)

    if (t < 63) {                      // stage Ks(t+1) (async DMA)
#pragma unroll
      for (int c = 0; c < 4; c++) {
        int R0 = w * 8 + 2 * c;
        int r = R0 + (l >> 5);
        gload_lds16(kbase + (size_t)(kt0 + 32 + r) * 8192 + (((l & 31) ^ (r & 7)) * 16),
                    &Ks[nb][R0 * 512]);
      }
      vreg = *(const uint4*)(vrow + kt0 + 32);        // V(t+1)
    }

    // S = Q*K^T: 32 q-rows x 32 k-cols per wave, E=512 inner (fp8)
    fx4 accS[2][2] = {};
#pragma unroll
    for (int e = 0; e < 16; e++) {
      int slot = (((2 * e + (quad >> 1)) ^ (lane15 & 7)) * 16) + (quad & 1) * 8;
      i64 b0 = *(const i64*)(&Ks[cb][lane15 * 512 + slot]);
      i64 b1 = *(const i64*)(&Ks[cb][(16 + lane15) * 512 + slot]);
      accS[0][0] = MFMA8(qf[0][e], b0, accS[0][0]);
      accS[1][0] = MFMA8(qf[1][e], b0, accS[1][0]);
      accS[0][1] = MFMA8(qf[0][e], b1, accS[0][1]);
      accS[1][1] = MFMA8(qf[1][e], b1, accS[1][1]);
    }

    // PV(t-1): independent accumulates, interleave with QK above
    if (t > 0) {
      accO[0][0] = MFMA(pf0, vf0, accO[0][0]); accO[1][0] = MFMA(pf1, vf0, accO[1][0]);
      accO[0][1] = MFMA(pf0, vf1, accO[0][1]); accO[1][1] = MFMA(pf1, vf1, accO[1][1]);
      accO[0][2] = MFMA(pf0, vf2, accO[0][2]); accO[1][2] = MFMA(pf1, vf2, accO[1][2]);
      accO[0][3] = MFMA(pf0, vf3, accO[0][3]); accO[1][3] = MFMA(pf1, vf3, accO[1][3]);
    }

    // fixed-shift exp (v_exp_f32 computes 2^x); store Ps(t) — no wait needed
#pragma unroll
    for (int mt = 0; mt < 2; mt++)
#pragma unroll
      for (int r = 0; r < 4; r++) {
        float p0 = __builtin_amdgcn_exp2f(__fmaf_rn(accS[mt][0][r], scale2, -Mb));
        float p1 = __builtin_amdgcn_exp2f(__fmaf_rn(accS[mt][1][r], scale2, -Mb));
        lpart[mt][r] += p0 + p1;
        Ps[w][(mt * 16 + quad * 4 + r) * 40 + lane15]      = f2bf(p0);
        Ps[w][(mt * 16 + quad * 4 + r) * 40 + 16 + lane15] = f2bf(p1);
      }
  }

  {  // tail: PV(63). V(63) is in buffer 63 & 1 == 1.
    const u16* vsb = &Vs[1][0];
    bh8 pf0 = *(const bh8*)(&Ps[w][lane15 * 40 + quad * 8]);
    bh8 pf1 = *(const bh8*)(&Ps[w][(16 + lane15) * 40 + quad * 8]);
#pragma unroll
    for (int di = 0; di < 4; di++) {
      bh8 vf = *(const bh8*)(vsb + (di * 16 + lane15) * 40 + quad * 8);
      accO[0][di] = MFMA(pf0, vf, accO[0][di]);
      accO[1][di] = MFMA(pf1, vf, accO[1][di]);
    }
  }

  // epilogue: reduce row-sums across the 16 lanes, normalize, store
#pragma unroll
  for (int mt = 0; mt < 2; mt++)
#pragma unroll
    for (int r = 0; r < 4; r++) {
      float s = lpart[mt][r];
      s += __shfl_xor(s, 1);
      s += __shfl_xor(s, 2);
      s += __shfl_xor(s, 4);
      s += __shfl_xor(s, 8);
      float inv = 1.0f / s;
      int row = q0 + w * 32 + mt * 16 + quad * 4 + r;
      u16* orow = vals + (size_t)(b * 2048 + row) * 512 + h * 64 + lane15;
#pragma unroll
      for (int di = 0; di < 4; di++) orow[di * 16] = f2bf(accO[mt][di][r] * inv);
    }
}

// ---------------- launch ----------------
extern "C" void kernel_launch(void* const* d_in, const int* in_sizes, int n_in,
                              void* d_out, int out_size, void* d_ws, size_t ws_size,
                              hipStream_t stream) {
  const float* x   = (const float*)d_in[0];
  const float* Wqk = (const float*)d_in[1];
  const float* bqk = (const float*)d_in[2];
  const float* Wv  = (const float*)d_in[3];
  const float* bv  = (const float*)d_in[4];
  const float* Wo  = (const float*)d_in[5];
  const float* bo  = (const float*)d_in[6];
  float* out = (float*)d_out;

  char* ws = (char*)d_ws;                     // total use: ~97 MB
  u16* x_bf  = (u16*)(ws);                    // 8192x512 bf16 (8 MB)
  u8*  x8    = (u8*)(ws + 8388608);           // 8192x512 fp8  (4 MB)
  u8*  wqk8  = (u8*)(ws + 12582912);          // 8192x512 fp8  (4 MB)
  u16* wvt   = (u16*)(ws + 16777216);         // 512x512
  u16* wot   = (u16*)(ws + 17301504);         // 512x512
  u16* vtbuf = (u16*)(ws + 17825792);         // 32x64x2048 (per-head V^T)
  u16* valsb = (u16*)(ws + 26214400);         // 8192x512
  u8*  qk8   = (u8*)(ws + 34603008);          // 8192x8192 fp8 (64 MB)

  cast_x2<<<4096, 256, 0, stream>>>(x, x_bf, x8);
  tcast8<<<dim3(256, 16), dim3(32, 8), 0, stream>>>(Wqk, wqk8, 512, 8192);
  tcast<<<dim3(16, 16),  dim3(32, 8), 0, stream>>>(Wv, wvt, 512, 512);
  tcast<<<dim3(16, 16),  dim3(32, 8), 0, stream>>>(Wo, wot, 512, 512);

  gemm8_bt<<<dim3(64, 64), 256, 0, stream>>>(x8, wqk8, bqk, qk8, 8192, 8192, 512);
  gemm_bt<3><<<dim3(4, 64), 256, 0, stream>>>(x_bf, wvt, bv, vtbuf, 8192, 512, 512);

  flash_attn<<<dim3(16, 8, 4), 256, 0, stream>>>(qk8, vtbuf, valsb);

  gemm_bt<0><<<dim3(4, 64), 256, 0, stream>>>(valsb, wot, bo, out, 8192, 512, 512);
}

// Round 15
// 318.723 us; speedup vs baseline: 1.2046x; 1.0102x over previous
//
#include <hip/hip_runtime.h>
#include <cstdint>
#include <cstddef>

// B=4 S=2048 E=512 H=8 HD=64.
// G1 (x@Wqk) in MX-scaled fp8 MFMA (16x16x128 f8f6f4, unit e8m0 scales) —
// the only path to fp8 full rate (m145->m148: 995->1628 TF). W scaled x256,
// descale 2^-8. QK^T fp8 (16x16x32); PV + other GEMMs bf16. Flash: 52KB LDS
// -> 3 blocks/CU, PV pipelined one iter behind QK (R11/R14 config, 142.8us).
typedef unsigned short u16;
typedef unsigned char u8;
typedef long i64;                                        // 64-bit on amdgcn
typedef __attribute__((ext_vector_type(8))) short bh8;   // 8 bf16 (4 VGPR)
typedef __attribute__((ext_vector_type(4))) float fx4;   // 4 f32 acc
typedef __attribute__((ext_vector_type(8))) int i32x8;   // 32 fp8 (8 VGPR)

__device__ __forceinline__ u16 f2bf(float f) {           // RNE f32->bf16
  unsigned int u = __float_as_uint(f);
  u += 0x7fffu + ((u >> 16) & 1u);
  return (u16)(u >> 16);
}

// RNE f32 -> OCP e4m3fn, flush below 2^-6 to 0. Callers keep |f| in range.
__device__ __forceinline__ u8 f2e4m3(float f) {
  unsigned int u = __float_as_uint(f);
  unsigned int s = (u >> 24) & 0x80u;
  unsigned int mag = u & 0x7fffffffu;
  mag += 0x7ffffu + ((mag >> 20) & 1u);     // RNE at 3 mantissa bits
  if (mag < 0x3C800000u) return (u8)s;      // < 2^-6 -> signed zero
  unsigned int e8 = (mag >> 23) - 120u;     // bias 127 -> 7
  unsigned int m8 = (mag >> 20) & 7u;
  return (u8)(s | (e8 << 3) | m8);
}

typedef __attribute__((address_space(1))) void g1_void;
typedef __attribute__((address_space(3))) void l3_void;
__device__ __forceinline__ void gload_lds16(const void* g, const void* lds) {
  // async global->LDS, 16B/lane; LDS dest = wave-uniform base + lane*16
  __builtin_amdgcn_global_load_lds((g1_void*)(uintptr_t)g,
                                   (l3_void*)(unsigned int)(uintptr_t)lds,
                                   16, 0, 0);
}

__device__ __forceinline__ fx4 MFMA(bh8 a, bh8 b, fx4 c) {
  return __builtin_amdgcn_mfma_f32_16x16x32_bf16(a, b, c, 0, 0, 0);
}
__device__ __forceinline__ fx4 MFMA8(i64 a, i64 b, fx4 c) {
  return __builtin_amdgcn_mfma_f32_16x16x32_fp8_fp8(a, b, c, 0, 0, 0);
}
// MX-scaled: K=128, A/B fmt = fp8 e4m3 (cbsz=0, blgp=0), scales = 1.0
// (e8m0 0x7F, byte 0). Lane layout: A[m=lane&15][k=(lane>>4)*32 + j], j<32.
__device__ __forceinline__ fx4 MFMAMX(i32x8 a, i32x8 b, fx4 c) {
  return __builtin_amdgcn_mfma_scale_f32_16x16x128_f8f6f4(a, b, c, 0, 0,
                                                          0, 0x7F, 0, 0x7F);
}
__device__ __forceinline__ i32x8 mk8(uint4 lo, uint4 hi) {
  i32x8 v;
  v[0] = (int)lo.x; v[1] = (int)lo.y; v[2] = (int)lo.z; v[3] = (int)lo.w;
  v[4] = (int)hi.x; v[5] = (int)hi.y; v[6] = (int)hi.z; v[7] = (int)hi.w;
  return v;
}

// ---------------- pre/post processing ----------------
// x f32 -> bf16 (for V-GEMM) and fp8 (for G1)
__global__ void cast_x2(const float* __restrict__ in, u16* __restrict__ outb,
                        u8* __restrict__ out8) {
  int i = blockIdx.x * 256 + threadIdx.x;           // grid sized exactly n/4
  float4 f = ((const float4*)in)[i];
  ushort4 u;
  u.x = f2bf(f.x); u.y = f2bf(f.y); u.z = f2bf(f.z); u.w = f2bf(f.w);
  ((ushort4*)outb)[i] = u;
  unsigned int p = (unsigned int)f2e4m3(f.x) | ((unsigned int)f2e4m3(f.y) << 8)
                 | ((unsigned int)f2e4m3(f.z) << 16) | ((unsigned int)f2e4m3(f.w) << 24);
  ((unsigned int*)out8)[i] = p;
}

// W[R][C] f32 -> Wt[C][R] bf16 (gemm_bt wants B as [N][K])
__global__ void tcast(const float* __restrict__ W, u16* __restrict__ Wt, int R, int C) {
  __shared__ float t[32][33];
  int tx = threadIdx.x, ty = threadIdx.y;
  int c0 = blockIdx.x * 32, r0 = blockIdx.y * 32;
#pragma unroll
  for (int i = 0; i < 4; i++)
    t[ty + i * 8][tx] = W[(size_t)(r0 + ty + i * 8) * C + c0 + tx];
  __syncthreads();
#pragma unroll
  for (int i = 0; i < 4; i++)
    Wt[(size_t)(c0 + ty + i * 8) * R + r0 + tx] = f2bf(t[tx][ty + i * 8]);
}

// W[R][C] f32 -> Wt[C][R] fp8, scaled x256 (exact pow2; descaled in GEMM)
__global__ void tcast8(const float* __restrict__ W, u8* __restrict__ Wt, int R, int C) {
  __shared__ float t[32][33];
  int tx = threadIdx.x, ty = threadIdx.y;
  int c0 = blockIdx.x * 32, r0 = blockIdx.y * 32;
#pragma unroll
  for (int i = 0; i < 4; i++)
    t[ty + i * 8][tx] = W[(size_t)(r0 + ty + i * 8) * C + c0 + tx];
  __syncthreads();
#pragma unroll
  for (int i = 0; i < 4; i++)
    Wt[(size_t)(c0 + ty + i * 8) * R + r0 + tx] = f2e4m3(t[tx][ty + i * 8] * 256.0f);
}

// ---------------- GEMM bf16: C[M][N] = A[M][K] * Bt[N][K]^T + bias --------
// m97 structure: 128x128 tile, BK=64, 4 waves each 64x64 (4x4 of 16x16).
// OUT_MODE: 0 = f32, 1 = bf16, 3 = bf16 scattered as per-head V^T:
// vt[(b*512 + col)*2048 + s].
template <int OUT_MODE>
__global__ __launch_bounds__(256) void gemm_bt(const u16* __restrict__ A,
                                               const u16* __restrict__ Bt,
                                               const float* __restrict__ bias,
                                               void* __restrict__ Cout,
                                               int M, int N, int K) {
  __shared__ u16 As[128 * 64];
  __shared__ u16 Bs[128 * 64];
  const int tid = threadIdx.x;
  const int l = tid & 63, w = tid >> 6;
  const int lane15 = l & 15, quad = l >> 4;
  const int wm = (w >> 1) * 64, wn = (w & 1) * 64;
  const int bm = blockIdx.y * 128, bn = blockIdx.x * 128;
  fx4 acc[4][4] = {};

  const int srow = w * 32 + (l >> 3);
  const int scol = ((l & 7) ^ (l >> 3)) * 8;      // swizzle: slot (l&7) <- chunk (l&7)^(row&7)
  const u16* Ag = A + (size_t)(bm + srow) * K + scol;
  const u16* Bg = Bt + (size_t)(bn + srow) * K + scol;

  for (int kt = 0; kt < K; kt += 64) {
    __syncthreads();
#pragma unroll
    for (int c = 0; c < 4; c++) {
      gload_lds16(Ag + (size_t)(c * 8) * K + kt, As + (w * 32 + c * 8) * 64);
      gload_lds16(Bg + (size_t)(c * 8) * K + kt, Bs + (w * 32 + c * 8) * 64);
    }
    __syncthreads();
#pragma unroll
    for (int kk8 = 0; kk8 < 8; kk8 += 4) {        // kk8 = kk/8, kk in {0,32}
      bh8 a[4], b[4];
#pragma unroll
      for (int mi = 0; mi < 4; mi++) {
        int r = wm + mi * 16 + lane15;
        a[mi] = *(const bh8*)(As + r * 64 + (((kk8 + quad) ^ (r & 7)) * 8));
      }
#pragma unroll
      for (int ni = 0; ni < 4; ni++) {
        int r = wn + ni * 16 + lane15;
        b[ni] = *(const bh8*)(Bs + r * 64 + (((kk8 + quad) ^ (r & 7)) * 8));
      }
#pragma unroll
      for (int mi = 0; mi < 4; mi++)
#pragma unroll
        for (int ni = 0; ni < 4; ni++)
          acc[mi][ni] = MFMA(a[mi], b[ni], acc[mi][ni]);
    }
  }
  // epilogue: C/D layout col=lane&15, row=quad*4+reg  [measured m89/m91]
#pragma unroll
  for (int mi = 0; mi < 4; mi++)
#pragma unroll
    for (int ni = 0; ni < 4; ni++) {
      int col = bn + wn + ni * 16 + lane15;
      float bv = bias[col];
#pragma unroll
      for (int r = 0; r < 4; r++) {
        int row = bm + wm + mi * 16 + quad * 4 + r;
        float v = acc[mi][ni][r] + bv;
        if (OUT_MODE == 3)
          ((u16*)Cout)[((size_t)((row >> 11) * 512 + col) << 11) + (row & 2047)] = f2bf(v);
        else if (OUT_MODE == 1) ((u16*)Cout)[(size_t)row * N + col] = f2bf(v);
        else                    ((float*)Cout)[(size_t)row * N + col] = v;
      }
    }
}

// ---------------- GEMM fp8 MX: C = (A8 * B8t^T) * 2^-8 + bias -> fp8 -------
// m97 skeleton, BK=128 fp8, ONE 16x16x128 scaled MFMA per (mi,ni) per K-tile
// (16 instrs/tile vs 64 K=32 instrs — MFMA issue time halves at the MX rate).
// Lane reads its 32 contiguous K bytes = two adjacent XOR-swizzled 16B slots.
__global__ __launch_bounds__(256) void gemm8_bt(const u8* __restrict__ A,
                                                const u8* __restrict__ Bt,
                                                const float* __restrict__ bias,
                                                u8* __restrict__ Cout,
                                                int M, int N, int K) {
  __shared__ u8 As[128 * 128];
  __shared__ u8 Bs[128 * 128];
  const int tid = threadIdx.x;
  const int l = tid & 63, w = tid >> 6;
  const int lane15 = l & 15, quad = l >> 4;
  const int wm = (w >> 1) * 64, wn = (w & 1) * 64;
  const int bm = blockIdx.y * 128, bn = blockIdx.x * 128;
  fx4 acc[4][4] = {};

  // staging: wave w covers rows w*32..+31 in 4 calls of 8 rows x 8 chunks
  const int srow = w * 32 + (l >> 3);
  const int scol = ((l & 7) ^ ((l >> 3) & 7)) * 16;
  const u8* Ag = A + (size_t)(bm + srow) * K + scol;
  const u8* Bg = Bt + (size_t)(bn + srow) * K + scol;

  const int q2 = quad * 2;             // first 16B chunk of this lane's 32B
  for (int kt = 0; kt < K; kt += 128) {
    __syncthreads();
#pragma unroll
    for (int c = 0; c < 4; c++) {
      gload_lds16(Ag + (size_t)(c * 8) * K + kt, As + (w * 32 + c * 8) * 128);
      gload_lds16(Bg + (size_t)(c * 8) * K + kt, Bs + (w * 32 + c * 8) * 128);
    }
    __syncthreads();
    i32x8 a[4], b[4];
#pragma unroll
    for (int mi = 0; mi < 4; mi++) {
      int r = wm + mi * 16 + lane15;
      const u8* rp = As + r * 128;
      a[mi] = mk8(*(const uint4*)(rp + ((q2 ^ (r & 7)) * 16)),
                  *(const uint4*)(rp + (((q2 + 1) ^ (r & 7)) * 16)));
    }
#pragma unroll
    for (int ni = 0; ni < 4; ni++) {
      int r = wn + ni * 16 + lane15;
      const u8* rp = Bs + r * 128;
      b[ni] = mk8(*(const uint4*)(rp + ((q2 ^ (r & 7)) * 16)),
                  *(const uint4*)(rp + (((q2 + 1) ^ (r & 7)) * 16)));
    }
#pragma unroll
    for (int mi = 0; mi < 4; mi++)
#pragma unroll
      for (int ni = 0; ni < 4; ni++)
        acc[mi][ni] = MFMAMX(a[mi], b[ni], acc[mi][ni]);
  }
  // epilogue: descale 2^-8 (W was quantized x256), add bias, store fp8
#pragma unroll
  for (int mi = 0; mi < 4; mi++)
#pragma unroll
    for (int ni = 0; ni < 4; ni++) {
      int col = bn + wn + ni * 16 + lane15;
      float bv = bias[col];
#pragma unroll
      for (int r = 0; r < 4; r++) {
        int row = bm + wm + mi * 16 + quad * 4 + r;
        Cout[(size_t)row * N + col] = f2e4m3(acc[mi][ni][r] * 0.00390625f + bv);
      }
    }
}

// ---------------- flash attention (unchanged R11/R14: 142.8 us measured) ---
__global__ __launch_bounds__(256, 3) void flash_attn(const u8* __restrict__ qk8,
                                                     const u16* __restrict__ vt,
                                                     u16* __restrict__ vals) {
  __shared__ __align__(16) u8 Ks[2][32 * 512];   // 32KB fp8, chunk-swizzled
  __shared__ __align__(16) u16 Vs[2][64 * 40];   // 10KB bf16, padded rows
  __shared__ __align__(16) u16 Ps[4][32 * 40];   // 10KB per-wave P
  const int tid = threadIdx.x;
  const int l = tid & 63, w = tid >> 6;
  const int lane15 = l & 15, quad = l >> 4;
  const int q0 = blockIdx.x * 128;
  const int h = blockIdx.y, b = blockIdx.z;
  const float scale2 = 0.063762531f;   // (1/sqrt(512)) * log2(e)
  const float Mb = 2.0f;               // fixed shift (log2 domain)

  i64 qf[2][16];
#pragma unroll
  for (int mt = 0; mt < 2; mt++) {
    const u8* qrow = qk8 + (size_t)(b * 2048 + q0 + w * 32 + mt * 16 + lane15) * 8192
                   + h * 1024 + quad * 8;
#pragma unroll
    for (int t = 0; t < 16; t++) qf[mt][t] = *(const i64*)(qrow + t * 32);
  }

  fx4 accO[2][4] = {};
  float lpart[2][4] = {};

  const u8* kbase = qk8 + (size_t)(b * 2048) * 8192 + h * 1024 + 512;
  const u16* vrow = vt + (size_t)((b * 8 + h) * 64 + (tid >> 2)) * 2048 + (tid & 3) * 8;
  const int vs_off = (tid >> 2) * 40 + (tid & 3) * 8;

  // prologue: stage Ks(0); vreg holds V(0)
  uint4 vreg = *(const uint4*)vrow;
#pragma unroll
  for (int c = 0; c < 4; c++) {
    int R0 = w * 8 + 2 * c;
    int r = R0 + (l >> 5);
    gload_lds16(kbase + (size_t)r * 8192 + (((l & 31) ^ (r & 7)) * 16),
                &Ks[0][R0 * 512]);
  }

  for (int t = 0; t < 64; t++) {
    const int cb = t & 1, nb = cb ^ 1;
    const int kt0 = t * 32;
    __syncthreads();                   // Ks(t)/Vs(t-1) landed; buffers free

    // PV(t-1) operands: issue early, consumed mid-iter (latency hidden)
    bh8 pf0, pf1, vf0, vf1, vf2, vf3;
    if (t > 0) {
      const u16* vsb = &Vs[(t - 1) & 1][0];           // V(t-1)
      pf0 = *(const bh8*)(&Ps[w][lane15 * 40 + quad * 8]);
      pf1 = *(const bh8*)(&Ps[w][(16 + lane15) * 40 + quad * 8]);
      vf0 = *(const bh8*)(vsb + (lane15)      * 40 + quad * 8);
      vf1 = *(const bh8*)(vsb + (16 + lane15) * 40 + quad * 8);
      vf2 = *(const bh8*)(vsb + (32 + lane15) * 40 + quad * 8);
      vf3 = *(const bh8*)(vsb + (48 + lane15) * 40 + quad * 8);
    }

    *(uint4*)&Vs[cb][vs_off] = vreg;   // stage V(t) (read by PV at iter t+1)

    if (t < 63) {                      // stage Ks(t+1) (async DMA)
#pragma unroll
      for (int c = 0; c < 4; c++) {
        int R0 = w * 8 + 2 * c;
        int r = R0 + (l >> 5);
        gload_lds16(kbase + (size_t)(kt0 + 32 + r) * 8192 + (((l & 31) ^ (r & 7)) * 16),
                    &Ks[nb][R0 * 512]);
      }
      vreg = *(const uint4*)(vrow + kt0 + 32);        // V(t+1)
    }

    // S = Q*K^T: 32 q-rows x 32 k-cols per wave, E=512 inner (fp8)
    fx4 accS[2][2] = {};
#pragma unroll
    for (int e = 0; e < 16; e++) {
      int slot = (((2 * e + (quad >> 1)) ^ (lane15 & 7)) * 16) + (quad & 1) * 8;
      i64 b0 = *(const i64*)(&Ks[cb][lane15 * 512 + slot]);
      i64 b1 = *(const i64*)(&Ks[cb][(16 + lane15) * 512 + slot]);
      accS[0][0] = MFMA8(qf[0][e], b0, accS[0][0]);
      accS[1][0] = MFMA8(qf[1][e], b0, accS[1][0]);
      accS[0][1] = MFMA8(qf[0][e], b1, accS[0][1]);
      accS[1][1] = MFMA8(qf[1][e], b1, accS[1][1]);
    }

    // PV(t-1): independent accumulates, interleave with QK above
    if (t > 0) {
      accO[0][0] = MFMA(pf0, vf0, accO[0][0]); accO[1][0] = MFMA(pf1, vf0, accO[1][0]);
      accO[0][1] = MFMA(pf0, vf1, accO[0][1]); accO[1][1] = MFMA(pf1, vf1, accO[1][1]);
      accO[0][2] = MFMA(pf0, vf2, accO[0][2]); accO[1][2] = MFMA(pf1, vf2, accO[1][2]);
      accO[0][3] = MFMA(pf0, vf3, accO[0][3]); accO[1][3] = MFMA(pf1, vf3, accO[1][3]);
    }

    // fixed-shift exp (v_exp_f32 computes 2^x); store Ps(t) — no wait needed
#pragma unroll
    for (int mt = 0; mt < 2; mt++)
#pragma unroll
      for (int r = 0; r < 4; r++) {
        float p0 = __builtin_amdgcn_exp2f(__fmaf_rn(accS[mt][0][r], scale2, -Mb));
        float p1 = __builtin_amdgcn_exp2f(__fmaf_rn(accS[mt][1][r], scale2, -Mb));
        lpart[mt][r] += p0 + p1;
        Ps[w][(mt * 16 + quad * 4 + r) * 40 + lane15]      = f2bf(p0);
        Ps[w][(mt * 16 + quad * 4 + r) * 40 + 16 + lane15] = f2bf(p1);
      }
  }

  {  // tail: PV(63). V(63) is in buffer 63 & 1 == 1.
    const u16* vsb = &Vs[1][0];
    bh8 pf0 = *(const bh8*)(&Ps[w][lane15 * 40 + quad * 8]);
    bh8 pf1 = *(const bh8*)(&Ps[w][(16 + lane15) * 40 + quad * 8]);
#pragma unroll
    for (int di = 0; di < 4; di++) {
      bh8 vf = *(const bh8*)(vsb + (di * 16 + lane15) * 40 + quad * 8);
      accO[0][di] = MFMA(pf0, vf, accO[0][di]);
      accO[1][di] = MFMA(pf1, vf, accO[1][di]);
    }
  }

  // epilogue: reduce row-sums across the 16 lanes, normalize, store
#pragma unroll
  for (int mt = 0; mt < 2; mt++)
#pragma unroll
    for (int r = 0; r < 4; r++) {
      float s = lpart[mt][r];
      s += __shfl_xor(s, 1);
      s += __shfl_xor(s, 2);
      s += __shfl_xor(s, 4);
      s += __shfl_xor(s, 8);
      float inv = 1.0f / s;
      int row = q0 + w * 32 + mt * 16 + quad * 4 + r;
      u16* orow = vals + (size_t)(b * 2048 + row) * 512 + h * 64 + lane15;
#pragma unroll
      for (int di = 0; di < 4; di++) orow[di * 16] = f2bf(accO[mt][di][r] * inv);
    }
}

// ---------------- launch ----------------
extern "C" void kernel_launch(void* const* d_in, const int* in_sizes, int n_in,
                              void* d_out, int out_size, void* d_ws, size_t ws_size,
                              hipStream_t stream) {
  const float* x   = (const float*)d_in[0];
  const float* Wqk = (const float*)d_in[1];
  const float* bqk = (const float*)d_in[2];
  const float* Wv  = (const float*)d_in[3];
  const float* bv  = (const float*)d_in[4];
  const float* Wo  = (const float*)d_in[5];
  const float* bo  = (const float*)d_in[6];
  float* out = (float*)d_out;

  char* ws = (char*)d_ws;                     // total use: ~97 MB
  u16* x_bf  = (u16*)(ws);                    // 8192x512 bf16 (8 MB)
  u8*  x8    = (u8*)(ws + 8388608);           // 8192x512 fp8  (4 MB)
  u8*  wqk8  = (u8*)(ws + 12582912);          // 8192x512 fp8  (4 MB)
  u16* wvt   = (u16*)(ws + 16777216);         // 512x512
  u16* wot   = (u16*)(ws + 17301504);         // 512x512
  u16* vtbuf = (u16*)(ws + 17825792);         // 32x64x2048 (per-head V^T)
  u16* valsb = (u16*)(ws + 26214400);         // 8192x512
  u8*  qk8   = (u8*)(ws + 34603008);          // 8192x8192 fp8 (64 MB)

  cast_x2<<<4096, 256, 0, stream>>>(x, x_bf, x8);
  tcast8<<<dim3(256, 16), dim3(32, 8), 0, stream>>>(Wqk, wqk8, 512, 8192);
  tcast<<<dim3(16, 16),  dim3(32, 8), 0, stream>>>(Wv, wvt, 512, 512);
  tcast<<<dim3(16, 16),  dim3(32, 8), 0, stream>>>(Wo, wot, 512, 512);

  gemm8_bt<<<dim3(64, 64), 256, 0, stream>>>(x8, wqk8, bqk, qk8, 8192, 8192, 512);
  gemm_bt<3><<<dim3(4, 64), 256, 0, stream>>>(x_bf, wvt, bv, vtbuf, 8192, 512, 512);

  flash_attn<<<dim3(16, 8, 4), 256, 0, stream>>>(qk8, vtbuf, valsb);

  gemm_bt<0><<<dim3(4, 64), 256, 0, stream>>>(valsb, wot, bo, out, 8192, 512, 512);
}